// Round 7
// baseline (175.815 us; speedup 1.0000x reference)
//
#include <hip/hip_runtime.h>

#define IMG 512
#define PAD 5
#define KW  11
#define SH  64                 // output rows per block strip
#define WCOLS 64               // output cols per wave
#define NWAVES 4
#define BW (WCOLS * NWAVES)    // 256 cols per block
#define STG (WCOLS + 2 * PAD)  // 74 staged cols per wave
#define NPLANES 48
#define NCHUNK 7               // 7*11 = 77 >= max 74 input rows

typedef float v2f __attribute__((ext_vector_type(2)));

// Packed-FP32 row-streaming SSIM.
// Round-6 evidence: VALU-issue volume (~62us) is the wall; neither occupancy
// nor register budget moved it. Fix: express all blur math as float2 pairs so
// the backend emits v_pk_fma_f32 (2 FMA/inst, the only path to the 157TF
// fp32 rate):
//   pair1 = (a, b)            -> blurred = (mu1, mu2)
//   pair2 = (a^2+b^2, 2ab)    -> blurred = (xs, 2*x12)
// built per tap as (a,a)*(a,b) + (b,b)*(b,a)  [opsel-foldable shuffles].
// Emit: 2*(x12-m12) = x2ab - 2*m12, s11+s22 = xs - mu1^2 - mu2^2.
// Gaussian weights are compile-time literals (g(d)=exp(-d^2/4.5), normalized).
__global__ __launch_bounds__(256, 2) void ssim_pk_kernel(
    const float* __restrict__ img1,
    const float* __restrict__ img2,
    double* __restrict__ accum)
{
    __shared__ v2f sbuf[NWAVES][STG + 1];   // ~2.4 KB

    // exp(-d^2/4.5)/sum, d = k-5 (symmetric).
#define W0 0.00102837f
#define W1 0.00759874f
#define W2 0.03600077f
#define W3 0.10936370f
#define W4 0.21300551f
#define W5 0.26601172f
    static constexpr float WK[KW] = {W0, W1, W2, W3, W4, W5, W4, W3, W2, W1, W0};

    const int tid   = threadIdx.x;
    const int wv_id = tid >> 6;
    const int lane  = tid & 63;
    const int plane = blockIdx.z;
    const int wc0   = blockIdx.x * BW + wv_id * WCOLS;
    const int y0    = blockIdx.y * SH;

    const float* __restrict__ A = img1 + (size_t)plane * (IMG * IMG);
    const float* __restrict__ B = img2 + (size_t)plane * (IMG * IMG);
    v2f* lbuf = &sbuf[wv_id][0];

    // Per-thread column addressing (constant across rows).
    const int c0  = wc0 - PAD + lane;            // main staged col
    const int cc0 = min(max(c0, 0), IMG - 1);
    const float m0 = (c0 >= 0 && c0 < IMG) ? 1.f : 0.f;
    const int c1  = wc0 + (WCOLS - PAD) + lane;  // edge staged col (lane<10)
    const int cc1 = min(c1, IMG - 1);
    const float m1 = (c1 < IMG) ? 1.f : 0.f;

    const int ystart = max(y0 - PAD, 0);
    const int yend   = min(y0 + SH + PAD, IMG);

    // Vertical pending accumulators: 2 pair-quantities x 11 slots (44 regs).
    v2f rmu[KW], rx[KW];
#pragma unroll
    for (int j = 0; j < KW; ++j) {
        rmu[j] = (v2f)0.f;
        rx[j]  = (v2f)0.f;
    }

    const float C1v = 1e-4f;
    const float C2v = 9e-4f;
    float local = 0.f;

    // Prefetch first row.
    const float* rowA = A + (size_t)ystart * IMG;
    const float* rowB = B + (size_t)ystart * IMG;
    float pa0 = rowA[cc0], pb0 = rowB[cc0];
    float pa1 = rowA[cc1], pb1 = rowB[cc1];

    int y = ystart;

    // SSIM evaluation of one completed slot (compile-time slot index).
#define SSIM_EMIT(sd)                                                          \
    {                                                                          \
        const float mu1 = rmu[sd].x, mu2 = rmu[sd].y;                          \
        const float xs  = rx[sd].x,  x2ab = rx[sd].y;  /* = 2*blur(ab) */      \
        const float m12 = mu1 * mu2;                                           \
        const float t2m = m12 + m12;                                           \
        const float num = (t2m + C1v) * ((x2ab - t2m) + C2v);                  \
        const float ssum = fmaf(mu1, mu1, mu2 * mu2);                          \
        const float den = (ssum + C1v) * ((xs - ssum) + C2v);                  \
        local += num * __builtin_amdgcn_rcpf(den);                             \
    }

#define SSIM_PHASE(p)                                                          \
    if (y < yend) {                                                            \
        /* stage current row (regs -> LDS, masked zeros for x-pad) */          \
        {                                                                      \
            v2f st; st.x = pa0 * m0; st.y = pb0 * m0;                          \
            lbuf[lane] = st;                                                   \
            if (lane < 2 * PAD) {                                              \
                v2f se; se.x = pa1 * m1; se.y = pb1 * m1;                      \
                lbuf[WCOLS + lane] = se;                                       \
            }                                                                  \
        }                                                                      \
        /* prefetch next row into regs (latency hidden under compute) */       \
        if (y + 1 < yend) {                                                    \
            rowA += IMG; rowB += IMG;                                          \
            pa0 = rowA[cc0]; pb0 = rowB[cc0];                                  \
            pa1 = rowA[cc1]; pb1 = rowB[cc1];                                  \
        }                                                                      \
        /* horizontal 11-tap blur, packed pairs */                             \
        v2f hmu = (v2f)0.f, hx = (v2f)0.f;                                     \
        _Pragma("unroll")                                                      \
        for (int k = 0; k < KW; ++k) {                                         \
            const v2f ab = lbuf[lane + k];            /* (a, b)   */           \
            v2f aa;  aa.x = ab.x;  aa.y = ab.x;       /* (a, a)   */           \
            v2f byy; byy.x = ab.y; byy.y = ab.y;      /* (b, b)   */           \
            v2f byx; byx.x = ab.y; byx.y = ab.x;      /* (b, a)   */           \
            v2f u = aa * ab;                          /* (a2, ab) */           \
            u = byy * byx + u;                        /* (a2+b2, 2ab) */       \
            const v2f wk2 = {WK[k], WK[k]};                                    \
            hmu = wk2 * ab + hmu;                                              \
            hx  = wk2 * u  + hx;                                               \
        }                                                                      \
        /* vertical scatter: y contributes to r=y-5+j, slot=(r-ystart)%11 */   \
        _Pragma("unroll")                                                      \
        for (int j = 0; j < KW; ++j) {                                         \
            const int sl = ((p) + 6 + j) % KW;                                 \
            const v2f wj2 = {WK[j], WK[j]};   /* w[10-j]==w[j] (symmetric) */  \
            rmu[sl] = wj2 * hmu + rmu[sl];                                     \
            rx[sl]  = wj2 * hx  + rx[sl];                                      \
        }                                                                      \
        /* emit completed output row r = y-5 */                                \
        {                                                                      \
            const int sd = ((p) + 6) % KW;                                     \
            const int r = y - PAD;                                             \
            if (r >= y0) SSIM_EMIT(sd);                                        \
            rmu[sd] = (v2f)0.f;                                                \
            rx[sd]  = (v2f)0.f;                                                \
        }                                                                      \
        ++y;                                                                   \
    }

#pragma unroll 1
    for (int chunk = 0; chunk < NCHUNK; ++chunk) {
        SSIM_PHASE(0) SSIM_PHASE(1) SSIM_PHASE(2) SSIM_PHASE(3)
        SSIM_PHASE(4) SSIM_PHASE(5) SSIM_PHASE(6) SSIM_PHASE(7)
        SSIM_PHASE(8) SSIM_PHASE(9) SSIM_PHASE(10)
    }
#undef SSIM_PHASE

    // Bottom strip: rows 507..511 truncate at y=511; flush their slots.
    // ystart=443 -> slot(r)=(r-443)%11: 507->9, 508->10, 509->0, 510->1, 511->2.
    if (blockIdx.y == (IMG / SH - 1)) {
        SSIM_EMIT(9) SSIM_EMIT(10) SSIM_EMIT(0) SSIM_EMIT(1) SSIM_EMIT(2)
    }
#undef SSIM_EMIT

    // Per-wave reduction + one atomic per wave.
#pragma unroll
    for (int off = 32; off > 0; off >>= 1)
        local += __shfl_down(local, off);
    if (lane == 0)
        atomicAdd(accum, (double)local);
}

__global__ void ssim_finalize_kernel(const double* __restrict__ accum,
                                     float* __restrict__ out)
{
    const double N = (double)NPLANES * IMG * IMG;
    out[0] = (float)(1.0 - accum[0] / N);
}

extern "C" void kernel_launch(void* const* d_in, const int* in_sizes, int n_in,
                              void* d_out, int out_size, void* d_ws, size_t ws_size,
                              hipStream_t stream) {
    const float* img1 = (const float*)d_in[0];
    const float* img2 = (const float*)d_in[1];
    float* out = (float*)d_out;
    double* accum = (double*)d_ws;   // 8 bytes used

    // d_ws is poisoned 0xAA before every call — zero the accumulator.
    hipMemsetAsync(accum, 0, sizeof(double), stream);

    dim3 grid(IMG / BW, IMG / SH, NPLANES);   // 2 x 8 x 48 = 768 blocks
    ssim_pk_kernel<<<grid, BW, 0, stream>>>(img1, img2, accum);
    ssim_finalize_kernel<<<1, 1, 0, stream>>>(accum, out);
}

// Round 8
// 159.614 us; speedup vs baseline: 1.1015x; 1.1015x over previous
//
#include <hip/hip_runtime.h>

#define IMG 512
#define PAD 5
#define KW  11
#define SH  32                 // output rows per block strip
#define WCOLS 64               // output cols per wave
#define NWAVES 4
#define BW (WCOLS * NWAVES)    // 256 cols per block
#define STG (WCOLS + 2 * PAD)  // 74 staged cols per wave
#define NPLANES 48
#define NSLOTS 64              // partial-sum slots (spread atomics)

typedef float v2f __attribute__((ext_vector_type(2)));

// Packed-FP32 row-streaming SSIM, latency-tolerant variant.
// Round-7 evidence: VALUBusy 40%, HBM 10%, occupancy 23.5% (grid-limited,
// 3 blocks/CU) with depth-1 prefetch vs ~900cy HBM latency => latency-bound.
// Fixes: SH 64->32 (1536 blocks -> 24 waves/CU supplied) and depth-2 row
// prefetch (row y issues loads for y+2; two reg sets role-swapped at compile
// time via 22-phase chunks). Math unchanged from round 7 (v_pk_fma_f32 pairs):
//   pair1 = (a, b)         -> (mu1, mu2)
//   pair2 = (a^2+b^2, 2ab) -> (xs, 2*x12)
__global__
__attribute__((amdgpu_flat_work_group_size(256, 256), amdgpu_waves_per_eu(4)))
void ssim_pk32_kernel(
    const float* __restrict__ img1,
    const float* __restrict__ img2,
    double* __restrict__ accum)
{
    __shared__ v2f sbuf[NWAVES][STG + 1];   // ~2.4 KB
    __shared__ float wsum[NWAVES];

    // exp(-d^2/4.5)/sum, d = k-5 (symmetric).
#define W0 0.00102837f
#define W1 0.00759874f
#define W2 0.03600077f
#define W3 0.10936370f
#define W4 0.21300551f
#define W5 0.26601172f
    static constexpr float WK[KW] = {W0, W1, W2, W3, W4, W5, W4, W3, W2, W1, W0};

    const int tid   = threadIdx.x;
    const int wv_id = tid >> 6;
    const int lane  = tid & 63;
    const int plane = blockIdx.z;
    const int wc0   = blockIdx.x * BW + wv_id * WCOLS;
    const int y0    = blockIdx.y * SH;

    const float* __restrict__ A = img1 + (size_t)plane * (IMG * IMG);
    const float* __restrict__ B = img2 + (size_t)plane * (IMG * IMG);
    v2f* lbuf = &sbuf[wv_id][0];

    // Per-thread column addressing (constant across rows).
    const int c0  = wc0 - PAD + lane;            // main staged col
    const int cc0 = min(max(c0, 0), IMG - 1);
    const float m0 = (c0 >= 0 && c0 < IMG) ? 1.f : 0.f;
    const int c1  = wc0 + (WCOLS - PAD) + lane;  // edge staged col (lane<10)
    const int cc1 = min(c1, IMG - 1);
    const float m1 = (c1 < IMG) ? 1.f : 0.f;

    const int ystart = max(y0 - PAD, 0);
    const int yend   = min(y0 + SH + PAD, IMG);  // <= 42 rows

    // Vertical pending accumulators: 2 pair-quantities x 11 slots (44 regs).
    v2f rmu[KW], rx[KW];
#pragma unroll
    for (int j = 0; j < KW; ++j) {
        rmu[j] = (v2f)0.f;
        rx[j]  = (v2f)0.f;
    }

    const float C1v = 1e-4f;
    const float C2v = 9e-4f;
    float local = 0.f;

    // Depth-2 prefetch: set X holds row y, set Y holds row y+1.
    float xa0, xb0, xa1, xb1, ya0, yb0, ya1, yb1;
    {
        const size_t r0 = (size_t)ystart * IMG;
        xa0 = A[r0 + cc0]; xb0 = B[r0 + cc0];
        xa1 = A[r0 + cc1]; xb1 = B[r0 + cc1];
        const int y1c = min(ystart + 1, yend - 1);
        const size_t r1 = (size_t)y1c * IMG;
        ya0 = A[r1 + cc0]; yb0 = B[r1 + cc0];
        ya1 = A[r1 + cc1]; yb1 = B[r1 + cc1];
    }

    int y = ystart;

    // SSIM evaluation of one completed slot (compile-time slot index).
#define SSIM_EMIT(sd)                                                          \
    {                                                                          \
        const float mu1 = rmu[sd].x, mu2 = rmu[sd].y;                          \
        const float xs  = rx[sd].x,  x2ab = rx[sd].y;  /* = 2*blur(ab) */      \
        const float m12 = mu1 * mu2;                                           \
        const float t2m = m12 + m12;                                           \
        const float num = (t2m + C1v) * ((x2ab - t2m) + C2v);                  \
        const float ssum = fmaf(mu1, mu1, mu2 * mu2);                          \
        const float den = (ssum + C1v) * ((xs - ssum) + C2v);                  \
        local += num * __builtin_amdgcn_rcpf(den);                             \
    }

    // One row-phase. C-regs hold row y; after staging they are reloaded with
    // row y+2 (the next phase's C is this phase's other set).
#define SSIM_PHASE(p, CA0, CB0, CA1, CB1)                                      \
    if (y < yend) {                                                            \
        {   /* stage row y (regs -> LDS, masked zeros for x-pad) */            \
            v2f st; st.x = CA0 * m0; st.y = CB0 * m0;                          \
            lbuf[lane] = st;                                                   \
            if (lane < 2 * PAD) {                                              \
                v2f se; se.x = CA1 * m1; se.y = CB1 * m1;                      \
                lbuf[WCOLS + lane] = se;                                       \
            }                                                                  \
        }                                                                      \
        {   /* issue loads for row y+2 into the freed C-regs */                \
            int yy = y + 2; if (yy > yend - 1) yy = yend - 1;                  \
            const size_t ro = (size_t)yy * IMG;                                \
            CA0 = A[ro + cc0]; CB0 = B[ro + cc0];                              \
            CA1 = A[ro + cc1]; CB1 = B[ro + cc1];                              \
        }                                                                      \
        /* horizontal 11-tap blur, packed pairs */                             \
        v2f hmu = (v2f)0.f, hx = (v2f)0.f;                                     \
        _Pragma("unroll")                                                      \
        for (int k = 0; k < KW; ++k) {                                         \
            const v2f ab = lbuf[lane + k];            /* (a, b)   */           \
            v2f aa;  aa.x = ab.x;  aa.y = ab.x;       /* (a, a)   */           \
            v2f byy; byy.x = ab.y; byy.y = ab.y;      /* (b, b)   */           \
            v2f byx; byx.x = ab.y; byx.y = ab.x;      /* (b, a)   */           \
            v2f u = aa * ab;                          /* (a2, ab) */           \
            u = byy * byx + u;                        /* (a2+b2, 2ab) */       \
            const v2f wk2 = {WK[k], WK[k]};                                    \
            hmu = wk2 * ab + hmu;                                              \
            hx  = wk2 * u  + hx;                                               \
        }                                                                      \
        /* vertical scatter: y contributes to r=y-5+j, slot=(r-ystart)%11 */   \
        _Pragma("unroll")                                                      \
        for (int j = 0; j < KW; ++j) {                                         \
            const int sl = ((p) + 6 + j) % KW;                                 \
            const v2f wj2 = {WK[j], WK[j]};   /* w[10-j]==w[j] (symmetric) */  \
            rmu[sl] = wj2 * hmu + rmu[sl];                                     \
            rx[sl]  = wj2 * hx  + rx[sl];                                      \
        }                                                                      \
        /* emit completed output row r = y-5 */                                \
        {                                                                      \
            const int sd = ((p) + 6) % KW;                                     \
            const int r = y - PAD;                                             \
            if (r >= y0) SSIM_EMIT(sd);                                        \
            rmu[sd] = (v2f)0.f;                                                \
            rx[sd]  = (v2f)0.f;                                                \
        }                                                                      \
        ++y;                                                                   \
    }

    // 22 phases per chunk (even count -> compile-time X/Y role swap);
    // 2 chunks x 22 = 44 >= max 42 input rows.
#pragma unroll 1
    for (int chunk = 0; chunk < 2; ++chunk) {
        SSIM_PHASE(0,  xa0, xb0, xa1, xb1)  SSIM_PHASE(1,  ya0, yb0, ya1, yb1)
        SSIM_PHASE(2,  xa0, xb0, xa1, xb1)  SSIM_PHASE(3,  ya0, yb0, ya1, yb1)
        SSIM_PHASE(4,  xa0, xb0, xa1, xb1)  SSIM_PHASE(5,  ya0, yb0, ya1, yb1)
        SSIM_PHASE(6,  xa0, xb0, xa1, xb1)  SSIM_PHASE(7,  ya0, yb0, ya1, yb1)
        SSIM_PHASE(8,  xa0, xb0, xa1, xb1)  SSIM_PHASE(9,  ya0, yb0, ya1, yb1)
        SSIM_PHASE(10, xa0, xb0, xa1, xb1)  SSIM_PHASE(11, ya0, yb0, ya1, yb1)
        SSIM_PHASE(12, xa0, xb0, xa1, xb1)  SSIM_PHASE(13, ya0, yb0, ya1, yb1)
        SSIM_PHASE(14, xa0, xb0, xa1, xb1)  SSIM_PHASE(15, ya0, yb0, ya1, yb1)
        SSIM_PHASE(16, xa0, xb0, xa1, xb1)  SSIM_PHASE(17, ya0, yb0, ya1, yb1)
        SSIM_PHASE(18, xa0, xb0, xa1, xb1)  SSIM_PHASE(19, ya0, yb0, ya1, yb1)
        SSIM_PHASE(20, xa0, xb0, xa1, xb1)  SSIM_PHASE(21, ya0, yb0, ya1, yb1)
    }
#undef SSIM_PHASE

    // Bottom strip (blockIdx.y==15, y0=480, ystart=475): rows 507..511
    // truncate at y=511; slot(r)=(r-475)%11 -> 507:10, 508:0, 509:1, 510:2, 511:3.
    if (blockIdx.y == (IMG / SH - 1)) {
        SSIM_EMIT(10) SSIM_EMIT(0) SSIM_EMIT(1) SSIM_EMIT(2) SSIM_EMIT(3)
    }
#undef SSIM_EMIT

    // Block reduction -> one atomic per block, spread over NSLOTS slots.
#pragma unroll
    for (int off = 32; off > 0; off >>= 1)
        local += __shfl_down(local, off);
    if (lane == 0) wsum[wv_id] = local;
    __syncthreads();
    if (tid == 0) {
        const float bs = wsum[0] + wsum[1] + wsum[2] + wsum[3];
        const int slot = (int)(((blockIdx.z * gridDim.y + blockIdx.y) * gridDim.x
                                + blockIdx.x) & (NSLOTS - 1));
        atomicAdd(&accum[slot], (double)bs);
    }
}

__global__ void ssim_finalize_kernel(const double* __restrict__ accum,
                                     float* __restrict__ out)
{
    double v = accum[threadIdx.x];
#pragma unroll
    for (int off = 32; off > 0; off >>= 1)
        v += __shfl_down(v, off);
    if (threadIdx.x == 0) {
        const double N = (double)NPLANES * IMG * IMG;
        out[0] = (float)(1.0 - v / N);
    }
}

extern "C" void kernel_launch(void* const* d_in, const int* in_sizes, int n_in,
                              void* d_out, int out_size, void* d_ws, size_t ws_size,
                              hipStream_t stream) {
    const float* img1 = (const float*)d_in[0];
    const float* img2 = (const float*)d_in[1];
    float* out = (float*)d_out;
    double* accum = (double*)d_ws;   // NSLOTS doubles

    // d_ws is poisoned 0xAA before every call — zero the accumulator slots.
    hipMemsetAsync(accum, 0, NSLOTS * sizeof(double), stream);

    dim3 grid(IMG / BW, IMG / SH, NPLANES);   // 2 x 16 x 48 = 1536 blocks
    ssim_pk32_kernel<<<grid, BW, 0, stream>>>(img1, img2, accum);
    ssim_finalize_kernel<<<1, 64, 0, stream>>>(accum, out);
}